// Round 4
// baseline (307.634 us; speedup 1.0000x reference)
//
#include <hip/hip_runtime.h>

#define B 8
#define C 256
#define P1 2048
#define P2 4096
#define CQ 32

typedef _Float16 h8 __attribute__((ext_vector_type(8)));
typedef _Float16 h4 __attribute__((ext_vector_type(4)));
typedef float f4 __attribute__((ext_vector_type(4)));

#define MFMA16(a, b, c) __builtin_amdgcn_mfma_f32_16x16x32_f16(a, b, c, 0, 0, 0)

// ---------------------------------------------------------------------------
// Convert weights to f16 hi/lo once. grid 32 x 256.
// ---------------------------------------------------------------------------
__global__ void prep_w(const float* __restrict__ Wq, const float* __restrict__ Wk,
                       const float* __restrict__ Wv,
                       _Float16* __restrict__ Wqh, _Float16* __restrict__ Wql,
                       _Float16* __restrict__ Wkh, _Float16* __restrict__ Wkl,
                       _Float16* __restrict__ Wvh) {
    const int i = blockIdx.x * 256 + threadIdx.x;
    if (i < CQ * C) {
        float a = Wq[i]; _Float16 h = (_Float16)a;
        Wqh[i] = h; Wql[i] = (_Float16)(a - (float)h);
        float b2 = Wk[i]; _Float16 h2 = (_Float16)b2;
        Wkh[i] = h2; Wkl[i] = (_Float16)(b2 - (float)h2);
    }
    for (int j = i; j < C * C; j += 32 * 256)
        Wvh[j] = (_Float16)Wv[j];
}

// ---------------------------------------------------------------------------
// prep1: from x1 compute q (hi/lo, [b][p][32], 3-pass) and v (hi, [b][c][p],
// 2-pass) via MFMA. grid (B, P1/32), block 256.
// ---------------------------------------------------------------------------
__global__ __launch_bounds__(256) void prep1(
        const float* __restrict__ x1,
        const _Float16* __restrict__ Wqh, const _Float16* __restrict__ Wql,
        const _Float16* __restrict__ Wvh,
        const float* __restrict__ bq, const float* __restrict__ bv,
        _Float16* __restrict__ qhw, _Float16* __restrict__ qlw,
        _Float16* __restrict__ vhw) {
    __shared__ float xs[32][257];
    const int t  = threadIdx.x;
    const int b  = blockIdx.x;
    const int p0 = blockIdx.y * 32;
    const float* xb = x1 + (size_t)b * C * P1;

    {
        const int pl = t & 31, cg = t >> 5;
#pragma unroll 8
        for (int i = 0; i < 32; ++i) {
            int c = cg * 32 + i;
            xs[pl][c] = xb[(size_t)c * P1 + p0 + pl];
        }
    }
    __syncthreads();

    const int w = t >> 6, lane = t & 63, ln = lane & 15, quad = lane >> 4;
    const int nh = w & 1, ch = w >> 1;
    const int prow = nh * 16 + ln;

    f4 accv[8];
#pragma unroll
    for (int mt = 0; mt < 8; ++mt) accv[mt] = (f4){0.f, 0.f, 0.f, 0.f};
    f4 accq = {0.f, 0.f, 0.f, 0.f};

    for (int ks = 0; ks < 8; ++ks) {
        const int c0 = ks * 32 + quad * 8;
        h8 bh, bl;
#pragma unroll
        for (int j = 0; j < 8; ++j) {
            float xv = xs[prow][c0 + j];
            _Float16 hh = (_Float16)xv;
            bh[j] = hh; bl[j] = (_Float16)(xv - (float)hh);
        }
#pragma unroll
        for (int mt = 0; mt < 8; ++mt) {
            h8 a = *(const h8*)&Wvh[(size_t)((ch * 8 + mt) * 16 + ln) * C + c0];
            accv[mt] = MFMA16(a, bh, accv[mt]);
            accv[mt] = MFMA16(a, bl, accv[mt]);
        }
        {
            h8 aqh = *(const h8*)&Wqh[(size_t)(ch * 16 + ln) * C + c0];
            h8 aql = *(const h8*)&Wql[(size_t)(ch * 16 + ln) * C + c0];
            accq = MFMA16(aql, bh, accq);
            accq = MFMA16(aqh, bl, accq);
            accq = MFMA16(aqh, bh, accq);
        }
    }

#pragma unroll
    for (int mt = 0; mt < 8; ++mt) {
        int cb = (ch * 8 + mt) * 16 + quad * 4;
        f4 bvv = *(const f4*)&bv[cb];
#pragma unroll
        for (int r = 0; r < 4; ++r)
            vhw[((size_t)b * C + cb + r) * P1 + p0 + prow] =
                (_Float16)(accv[mt][r] + bvv[r]);
    }
    {
        int ob = ch * 16 + quad * 4;
        f4 bqv = *(const f4*)&bq[ob];
        h4 hv, lv;
#pragma unroll
        for (int r = 0; r < 4; ++r) {
            float val = accq[r] + bqv[r];
            _Float16 hh = (_Float16)val;
            hv[r] = hh; lv[r] = (_Float16)(val - (float)hh);
        }
        size_t row = ((size_t)b * P1 + p0 + prow) * CQ + ob;
        *(h4*)(qhw + row) = hv;
        *(h4*)(qlw + row) = lv;
    }
}

// ---------------------------------------------------------------------------
// prep2: k (hi/lo, [b][q][32], 3-pass) from x2. grid (B, P2/32), block 256.
// ---------------------------------------------------------------------------
__global__ __launch_bounds__(256) void prep2(
        const float* __restrict__ x2,
        const _Float16* __restrict__ Wkh, const _Float16* __restrict__ Wkl,
        const float* __restrict__ bk,
        _Float16* __restrict__ khw, _Float16* __restrict__ klw) {
    __shared__ float xs[32][257];
    const int t  = threadIdx.x;
    const int b  = blockIdx.x;
    const int p0 = blockIdx.y * 32;
    const float* xb = x2 + (size_t)b * C * P2;
    {
        const int pl = t & 31, cg = t >> 5;
#pragma unroll 8
        for (int i = 0; i < 32; ++i) {
            int c = cg * 32 + i;
            xs[pl][c] = xb[(size_t)c * P2 + p0 + pl];
        }
    }
    __syncthreads();

    const int w = t >> 6, lane = t & 63, ln = lane & 15, quad = lane >> 4;
    const int nh = w & 1, mh = w >> 1;
    const int prow = nh * 16 + ln;

    f4 accq = {0.f, 0.f, 0.f, 0.f};
    for (int ks = 0; ks < 8; ++ks) {
        const int c0 = ks * 32 + quad * 8;
        h8 bh, bl;
#pragma unroll
        for (int j = 0; j < 8; ++j) {
            float xv = xs[prow][c0 + j];
            _Float16 hh = (_Float16)xv;
            bh[j] = hh; bl[j] = (_Float16)(xv - (float)hh);
        }
        h8 akh = *(const h8*)&Wkh[(size_t)(mh * 16 + ln) * C + c0];
        h8 akl = *(const h8*)&Wkl[(size_t)(mh * 16 + ln) * C + c0];
        accq = MFMA16(akl, bh, accq);
        accq = MFMA16(akh, bl, accq);
        accq = MFMA16(akh, bh, accq);
    }
    {
        int ob = mh * 16 + quad * 4;
        f4 bkv = *(const f4*)&bk[ob];
        h4 hv, lv;
#pragma unroll
        for (int r = 0; r < 4; ++r) {
            float val = accq[r] + bkv[r];
            _Float16 hh = (_Float16)val;
            hv[r] = hh; lv[r] = (_Float16)(val - (float)hh);
        }
        size_t row = ((size_t)b * P2 + p0 + prow) * CQ + ob;
        *(h4*)(khw + row) = hv;
        *(h4*)(klw + row) = lv;
    }
}

// ---------------------------------------------------------------------------
// stats: linv[b][p] = 1 / sum_q exp(energy[p][q]); 3-pass hi/lo f16 MFMA.
// block 512 = 8 waves = (2 p-subtiles x 4 q-quarters); p-tile 32/block.
// grid 512 linear, b = id&7 (XCD-pinned: each XCD L2 serves one k slice).
// 2 blocks/CU = 16 waves/CU.
// ---------------------------------------------------------------------------
__global__ __launch_bounds__(512) void stats_l(
        const _Float16* __restrict__ qhi, const _Float16* __restrict__ qlo,
        const _Float16* __restrict__ khi, const _Float16* __restrict__ klo,
        float* __restrict__ linv) {
    __shared__ float lred[2][4][16];
    const int t  = threadIdx.x;
    const int b  = blockIdx.x & 7;
    const int p0 = (blockIdx.x >> 3) * 32;
    const int w = t >> 6, lane = t & 63, ln = lane & 15, quad = lane >> 4;
    const int ptw = w & 1, qq = w >> 1;
    const int pbase = p0 + ptw * 16;

    h8 qh = *(const h8*)(qhi + ((size_t)b * P1 + pbase + ln) * CQ + quad * 8);
    h8 ql = *(const h8*)(qlo + ((size_t)b * P1 + pbase + ln) * CQ + quad * 8);

    f4 acc = {0.f, 0.f, 0.f, 0.f};
    const _Float16* khb = khi + (size_t)b * P2 * CQ;
    const _Float16* klb = klo + (size_t)b * P2 * CQ;

    for (int qc = qq * 1024; qc < qq * 1024 + 1024; qc += 32) {
#pragma unroll
        for (int tile = 0; tile < 2; ++tile) {
            int q = qc + tile * 16 + ln;
            h8 kh = *(const h8*)(khb + (size_t)q * CQ + quad * 8);
            h8 kl = *(const h8*)(klb + (size_t)q * CQ + quad * 8);
            f4 z = {0.f, 0.f, 0.f, 0.f};
            f4 e = MFMA16(ql, kh, z);
            e = MFMA16(qh, kl, e);
            e = MFMA16(qh, kh, e);
#pragma unroll
            for (int r = 0; r < 4; ++r) acc[r] += __expf(e[r]);
        }
    }
#pragma unroll
    for (int off = 1; off < 16; off <<= 1) {
#pragma unroll
        for (int r = 0; r < 4; ++r) acc[r] += __shfl_xor(acc[r], off);
    }
    if (ln == 0) *(f4*)&lred[ptw][qq][quad * 4] = acc;
    __syncthreads();
    if (t < 32) {
        int pw = t >> 4, pp = t & 15;
        float s = lred[pw][0][pp] + lred[pw][1][pp] +
                  lred[pw][2][pp] + lred[pw][3][pp];
        linv[(size_t)b * P1 + p0 + pw * 16 + pp] = 1.0f / s;
    }
}

// ---------------------------------------------------------------------------
// Fused attention-out GEMM. Tile: FULL C=256 x q-32, p chunks of 128.
// grid 1024 linear (b = id&7 XCD-pinned, 128 q-tiles per b) -> 4 blocks/CU,
// 16 waves/CU. 4 waves: energy p-subrange wc*32..+32; out c-quarter wc*64.
// Double-buffered att LDS, ONE barrier per chunk (16 barriers total).
// q-frag prefetch placed after energy phase so it overlaps the out-GEMM.
// ---------------------------------------------------------------------------
__global__ __launch_bounds__(256, 4) void attn_gemm(
        const _Float16* __restrict__ qhi, const _Float16* __restrict__ qlo,
        const _Float16* __restrict__ khi, const _Float16* __restrict__ klo,
        const _Float16* __restrict__ vhi, const float* __restrict__ linv,
        const float* __restrict__ x2, const float* __restrict__ alpha_p,
        float* __restrict__ out) {
    __shared__ _Float16 att_s[2][32][128];   // 16 KB total, XOR-swizzled

    const int t  = threadIdx.x;
    const int b  = blockIdx.x & 7;
    const int q0 = (blockIdx.x >> 3) * 32;
    const int wc = t >> 6;
    const int lane = t & 63, ln = lane & 15, quad = lane >> 4;
    const int sw = ln & 7;

    // resident k fragments for this block's 32 q's
    h8 kh[2], kl[2];
#pragma unroll
    for (int nt = 0; nt < 2; ++nt) {
        int q = q0 + nt * 16 + ln;
        kh[nt] = *(const h8*)(khi + ((size_t)b * P2 + q) * CQ + quad * 8);
        kl[nt] = *(const h8*)(klo + ((size_t)b * P2 + q) * CQ + quad * 8);
    }

    f4 acc[4][2];
#pragma unroll
    for (int mt = 0; mt < 4; ++mt)
#pragma unroll
        for (int nt = 0; nt < 2; ++nt) acc[mt][nt] = (f4){0.f, 0.f, 0.f, 0.f};

    // q frags for chunk 0 (this wave's p range: wc*32 .. wc*32+32)
    h8 cqh[2], cql[2];
#pragma unroll
    for (int pt = 0; pt < 2; ++pt) {
        size_t r = ((size_t)b * P1 + wc * 32 + pt * 16 + ln) * CQ + quad * 8;
        cqh[pt] = *(const h8*)(qhi + r);
        cql[pt] = *(const h8*)(qlo + r);
    }

    for (int pc = 0; pc < P1 / 128; ++pc) {
        const int p0v = pc * 128;
        f4 lv[2];
#pragma unroll
        for (int pt = 0; pt < 2; ++pt)
            lv[pt] = *(const f4*)(linv + (size_t)b * P1 + p0v + wc * 32 + pt * 16 + quad * 4);

        _Float16* abuf = &att_s[pc & 1][0][0];
        // ---- energy + att for p range [wc*32, wc*32+32) ----
#pragma unroll
        for (int pt = 0; pt < 2; ++pt) {
            int g   = wc * 4 + pt * 2 + (quad >> 1);
            int col = ((g ^ sw) << 3) + (quad & 1) * 4;
#pragma unroll
            for (int nt = 0; nt < 2; ++nt) {
                f4 z = {0.f, 0.f, 0.f, 0.f};
                f4 e = MFMA16(cql[pt], kh[nt], z);
                e = MFMA16(cqh[pt], kl[nt], e);
                e = MFMA16(cqh[pt], kh[nt], e);
                h4 pk;
#pragma unroll
                for (int r = 0; r < 4; ++r)
                    pk[r] = (_Float16)(__expf(e[r]) * lv[pt][r]);
                *(h4*)&abuf[(nt * 16 + ln) * 128 + col] = pk;
            }
        }
        __syncthreads();

        // prefetch next chunk's q frags (overlaps out-GEMM below)
        if (pc + 1 < P1 / 128) {
#pragma unroll
            for (int pt = 0; pt < 2; ++pt) {
                size_t r = ((size_t)b * P1 + p0v + 128 + wc * 32 + pt * 16 + ln) * CQ + quad * 8;
                cqh[pt] = *(const h8*)(qhi + r);
                cql[pt] = *(const h8*)(qlo + r);
            }
        }

        // ---- out GEMM over this p chunk (hi-only v) ----
#pragma unroll
        for (int kk = 0; kk < 128; kk += 32) {
            h8 bf[2];
#pragma unroll
            for (int nt = 0; nt < 2; ++nt) {
                int g2 = (kk >> 3) + quad;
                bf[nt] = *(const h8*)&abuf[(nt * 16 + ln) * 128 + ((g2 ^ sw) << 3)];
            }
            h8 av[4];
#pragma unroll
            for (int mt = 0; mt < 4; ++mt) {
                size_t off = ((size_t)b * C + wc * 64 + mt * 16 + ln) * P1
                           + p0v + kk + quad * 8;
                av[mt] = *(const h8*)(vhi + off);
            }
#pragma unroll
            for (int mt = 0; mt < 4; ++mt)
#pragma unroll
                for (int nt = 0; nt < 2; ++nt)
                    acc[mt][nt] = MFMA16(av[mt], bf[nt], acc[mt][nt]);
        }
        // double-buffer: next chunk's barrier orders its writes vs our reads
    }

    const float alpha = alpha_p[0];
#pragma unroll
    for (int mt = 0; mt < 4; ++mt) {
#pragma unroll
        for (int nt = 0; nt < 2; ++nt) {
            int q = q0 + nt * 16 + ln;
#pragma unroll
            for (int r = 0; r < 4; ++r) {
                int c = wc * 64 + mt * 16 + quad * 4 + r;
                size_t o = ((size_t)b * C + c) * P2 + q;
                out[o] = fmaf(alpha, acc[mt][nt][r], x2[o]);
            }
        }
    }
}

// ---------------------------------------------------------------------------
extern "C" void kernel_launch(void* const* d_in, const int* in_sizes, int n_in,
                              void* d_out, int out_size, void* d_ws, size_t ws_size,
                              hipStream_t stream) {
    const float* x1    = (const float*)d_in[0];
    const float* x2    = (const float*)d_in[1];
    const float* Wq    = (const float*)d_in[2];
    const float* bq    = (const float*)d_in[3];
    const float* Wk    = (const float*)d_in[4];
    const float* bk    = (const float*)d_in[5];
    const float* Wv    = (const float*)d_in[6];
    const float* bv    = (const float*)d_in[7];
    const float* alpha = (const float*)d_in[8];
    float* out = (float*)d_out;

    _Float16* qh = (_Float16*)d_ws;                     // [B][P1][32]
    _Float16* ql = qh + (size_t)B * P1 * CQ;
    _Float16* kh = ql + (size_t)B * P1 * CQ;            // [B][P2][32]
    _Float16* kl = kh + (size_t)B * P2 * CQ;
    _Float16* vh = kl + (size_t)B * P2 * CQ;            // [B][C][P1]
    _Float16* wqh = vh + (size_t)B * C * P1;            // [32][256]
    _Float16* wql = wqh + CQ * C;
    _Float16* wkh = wql + CQ * C;
    _Float16* wkl = wkh + CQ * C;
    _Float16* wvh = wkl + CQ * C;                       // [256][256]
    float*    li  = (float*)(wvh + C * C);              // [B][P1]

    prep_w<<<dim3(32), 256, 0, stream>>>(Wq, Wk, Wv, wqh, wql, wkh, wkl, wvh);
    prep1<<<dim3(B, P1 / 32), 256, 0, stream>>>(x1, wqh, wql, wvh, bq, bv, qh, ql, vh);
    prep2<<<dim3(B, P2 / 32), 256, 0, stream>>>(x2, wkh, wkl, bk, kh, kl);
    stats_l<<<dim3(512), 512, 0, stream>>>(qh, ql, kh, kl, li);
    attn_gemm<<<dim3(1024), 256, 0, stream>>>(qh, ql, kh, kl, vh, li, x2, alpha, out);
}

// Round 5
// 286.116 us; speedup vs baseline: 1.0752x; 1.0752x over previous
//
#include <hip/hip_runtime.h>

#define B 8
#define C 256
#define P1 2048
#define P2 4096
#define CQ 32

typedef _Float16 h8 __attribute__((ext_vector_type(8)));
typedef _Float16 h4 __attribute__((ext_vector_type(4)));
typedef float f4 __attribute__((ext_vector_type(4)));

#define MFMA16(a, b, c) __builtin_amdgcn_mfma_f32_16x16x32_f16(a, b, c, 0, 0, 0)

// ---------------------------------------------------------------------------
// Convert weights to f16 hi/lo once. grid 32 x 256.
// ---------------------------------------------------------------------------
__global__ void prep_w(const float* __restrict__ Wq, const float* __restrict__ Wk,
                       const float* __restrict__ Wv,
                       _Float16* __restrict__ Wqh, _Float16* __restrict__ Wql,
                       _Float16* __restrict__ Wkh, _Float16* __restrict__ Wkl,
                       _Float16* __restrict__ Wvh) {
    const int i = blockIdx.x * 256 + threadIdx.x;
    if (i < CQ * C) {
        float a = Wq[i]; _Float16 h = (_Float16)a;
        Wqh[i] = h; Wql[i] = (_Float16)(a - (float)h);
        float b2 = Wk[i]; _Float16 h2 = (_Float16)b2;
        Wkh[i] = h2; Wkl[i] = (_Float16)(b2 - (float)h2);
    }
    for (int j = i; j < C * C; j += 32 * 256)
        Wvh[j] = (_Float16)Wv[j];
}

// ---------------------------------------------------------------------------
// prep1: from x1 compute q (hi/lo, [b][p][32], 3-pass) and v (hi, [b][c][p],
// 2-pass) via MFMA. grid (B, P1/32), block 256.
// ---------------------------------------------------------------------------
__global__ __launch_bounds__(256) void prep1(
        const float* __restrict__ x1,
        const _Float16* __restrict__ Wqh, const _Float16* __restrict__ Wql,
        const _Float16* __restrict__ Wvh,
        const float* __restrict__ bq, const float* __restrict__ bv,
        _Float16* __restrict__ qhw, _Float16* __restrict__ qlw,
        _Float16* __restrict__ vhw) {
    __shared__ float xs[32][257];
    const int t  = threadIdx.x;
    const int b  = blockIdx.x;
    const int p0 = blockIdx.y * 32;
    const float* xb = x1 + (size_t)b * C * P1;

    {
        const int pl = t & 31, cg = t >> 5;
#pragma unroll 8
        for (int i = 0; i < 32; ++i) {
            int c = cg * 32 + i;
            xs[pl][c] = xb[(size_t)c * P1 + p0 + pl];
        }
    }
    __syncthreads();

    const int w = t >> 6, lane = t & 63, ln = lane & 15, quad = lane >> 4;
    const int nh = w & 1, ch = w >> 1;
    const int prow = nh * 16 + ln;

    f4 accv[8];
#pragma unroll
    for (int mt = 0; mt < 8; ++mt) accv[mt] = (f4){0.f, 0.f, 0.f, 0.f};
    f4 accq = {0.f, 0.f, 0.f, 0.f};

    for (int ks = 0; ks < 8; ++ks) {
        const int c0 = ks * 32 + quad * 8;
        h8 bh, bl;
#pragma unroll
        for (int j = 0; j < 8; ++j) {
            float xv = xs[prow][c0 + j];
            _Float16 hh = (_Float16)xv;
            bh[j] = hh; bl[j] = (_Float16)(xv - (float)hh);
        }
#pragma unroll
        for (int mt = 0; mt < 8; ++mt) {
            h8 a = *(const h8*)&Wvh[(size_t)((ch * 8 + mt) * 16 + ln) * C + c0];
            accv[mt] = MFMA16(a, bh, accv[mt]);
            accv[mt] = MFMA16(a, bl, accv[mt]);
        }
        {
            h8 aqh = *(const h8*)&Wqh[(size_t)(ch * 16 + ln) * C + c0];
            h8 aql = *(const h8*)&Wql[(size_t)(ch * 16 + ln) * C + c0];
            accq = MFMA16(aql, bh, accq);
            accq = MFMA16(aqh, bl, accq);
            accq = MFMA16(aqh, bh, accq);
        }
    }

#pragma unroll
    for (int mt = 0; mt < 8; ++mt) {
        int cb = (ch * 8 + mt) * 16 + quad * 4;
        f4 bvv = *(const f4*)&bv[cb];
#pragma unroll
        for (int r = 0; r < 4; ++r)
            vhw[((size_t)b * C + cb + r) * P1 + p0 + prow] =
                (_Float16)(accv[mt][r] + bvv[r]);
    }
    {
        int ob = ch * 16 + quad * 4;
        f4 bqv = *(const f4*)&bq[ob];
        h4 hv, lv;
#pragma unroll
        for (int r = 0; r < 4; ++r) {
            float val = accq[r] + bqv[r];
            _Float16 hh = (_Float16)val;
            hv[r] = hh; lv[r] = (_Float16)(val - (float)hh);
        }
        size_t row = ((size_t)b * P1 + p0 + prow) * CQ + ob;
        *(h4*)(qhw + row) = hv;
        *(h4*)(qlw + row) = lv;
    }
}

// ---------------------------------------------------------------------------
// prep2: k (hi/lo, [b][q][32], 3-pass) from x2. grid (B, P2/32), block 256.
// ---------------------------------------------------------------------------
__global__ __launch_bounds__(256) void prep2(
        const float* __restrict__ x2,
        const _Float16* __restrict__ Wkh, const _Float16* __restrict__ Wkl,
        const float* __restrict__ bk,
        _Float16* __restrict__ khw, _Float16* __restrict__ klw) {
    __shared__ float xs[32][257];
    const int t  = threadIdx.x;
    const int b  = blockIdx.x;
    const int p0 = blockIdx.y * 32;
    const float* xb = x2 + (size_t)b * C * P2;
    {
        const int pl = t & 31, cg = t >> 5;
#pragma unroll 8
        for (int i = 0; i < 32; ++i) {
            int c = cg * 32 + i;
            xs[pl][c] = xb[(size_t)c * P2 + p0 + pl];
        }
    }
    __syncthreads();

    const int w = t >> 6, lane = t & 63, ln = lane & 15, quad = lane >> 4;
    const int nh = w & 1, mh = w >> 1;
    const int prow = nh * 16 + ln;

    f4 accq = {0.f, 0.f, 0.f, 0.f};
    for (int ks = 0; ks < 8; ++ks) {
        const int c0 = ks * 32 + quad * 8;
        h8 bh, bl;
#pragma unroll
        for (int j = 0; j < 8; ++j) {
            float xv = xs[prow][c0 + j];
            _Float16 hh = (_Float16)xv;
            bh[j] = hh; bl[j] = (_Float16)(xv - (float)hh);
        }
        h8 akh = *(const h8*)&Wkh[(size_t)(mh * 16 + ln) * C + c0];
        h8 akl = *(const h8*)&Wkl[(size_t)(mh * 16 + ln) * C + c0];
        accq = MFMA16(akl, bh, accq);
        accq = MFMA16(akh, bl, accq);
        accq = MFMA16(akh, bh, accq);
    }
    {
        int ob = mh * 16 + quad * 4;
        f4 bkv = *(const f4*)&bk[ob];
        h4 hv, lv;
#pragma unroll
        for (int r = 0; r < 4; ++r) {
            float val = accq[r] + bkv[r];
            _Float16 hh = (_Float16)val;
            hv[r] = hh; lv[r] = (_Float16)(val - (float)hh);
        }
        size_t row = ((size_t)b * P2 + p0 + prow) * CQ + ob;
        *(h4*)(khw + row) = hv;
        *(h4*)(klw + row) = lv;
    }
}

// ---------------------------------------------------------------------------
// stats: linv[b][p] = 1 / sum_q exp(energy[p][q]).
// SINGLE-pass f16 (qh*kh only): l rel error ~0.2% -> out error <= ~0.01,
// well inside budget; halves k traffic, 1/3 the MFMA.
// block 512 = 8 waves = 2 p-16 tiles x 4 q-quarters; p-tile 32/block.
// grid 512 linear (b = id&7 XCD-pinned) -> 2 blocks/CU, 16 waves/CU.
// ---------------------------------------------------------------------------
__global__ __launch_bounds__(512) void stats_l(
        const _Float16* __restrict__ qhi, const _Float16* __restrict__ khi,
        float* __restrict__ linv) {
    __shared__ float lred[2][4][16];
    const int t  = threadIdx.x;
    const int b  = blockIdx.x & 7;
    const int p0 = (blockIdx.x >> 3) * 32;
    const int w = t >> 6, lane = t & 63, ln = lane & 15, quad = lane >> 4;
    const int ptw = w & 1, qq = w >> 1;
    const int pbase = p0 + ptw * 16;

    h8 qh = *(const h8*)(qhi + ((size_t)b * P1 + pbase + ln) * CQ + quad * 8);

    f4 acc = {0.f, 0.f, 0.f, 0.f};
    const _Float16* khb = khi + (size_t)b * P2 * CQ;

    for (int qc = qq * 1024; qc < qq * 1024 + 1024; qc += 32) {
        h8 kh0 = *(const h8*)(khb + (size_t)(qc + ln) * CQ + quad * 8);
        h8 kh1 = *(const h8*)(khb + (size_t)(qc + 16 + ln) * CQ + quad * 8);
        f4 z = {0.f, 0.f, 0.f, 0.f};
        f4 e0 = MFMA16(qh, kh0, z);
        f4 e1 = MFMA16(qh, kh1, z);
#pragma unroll
        for (int r = 0; r < 4; ++r) acc[r] += __expf(e0[r]) + __expf(e1[r]);
    }
#pragma unroll
    for (int off = 1; off < 16; off <<= 1) {
#pragma unroll
        for (int r = 0; r < 4; ++r) acc[r] += __shfl_xor(acc[r], off);
    }
    if (ln == 0) *(f4*)&lred[ptw][qq][quad * 4] = acc;
    __syncthreads();
    if (t < 32) {
        int pw = t >> 4, pp = t & 15;
        float s = lred[pw][0][pp] + lred[pw][1][pp] +
                  lred[pw][2][pp] + lred[pw][3][pp];
        linv[(size_t)b * P1 + p0 + pw * 16 + pp] = 1.0f / s;
    }
}

// ---------------------------------------------------------------------------
// Fused attention-out GEMM. Block 512 thr (8 waves), tile C-256 x q-64,
// p-chunks of 128. Energy: each wave owns one p-16 tile of the chunk (no
// duplication). Out: waves = 4 c-quarters x 2 q-halves (q-half pair's
// duplicate v reads hit L1). grid 512 = 64 q-tiles x 8 b (XCD-pinned) ->
// 2 blocks/CU = 16 waves/CU. att LDS double-buffered, 1 barrier/chunk.
// ---------------------------------------------------------------------------
__global__ __launch_bounds__(512, 4) void attn_gemm(
        const _Float16* __restrict__ qhi, const _Float16* __restrict__ qlo,
        const _Float16* __restrict__ khi, const _Float16* __restrict__ klo,
        const _Float16* __restrict__ vhi, const float* __restrict__ linv,
        const float* __restrict__ x2, const float* __restrict__ alpha_p,
        float* __restrict__ out) {
    __shared__ _Float16 att_s[2][64][128];   // 32 KB, XOR-swizzled 8-granules

    const int t  = threadIdx.x;
    const int b  = blockIdx.x & 7;
    const int q0 = (blockIdx.x >> 3) * 64;
    const int w  = t >> 6;                  // wave 0..7
    const int wc = w & 3, qh_half = w >> 2; // out-GEMM role
    const int lane = t & 63, ln = lane & 15, quad = lane >> 4;
    const int sw = ln & 7;

    // k fragments for the block's 64 q's (all nt needed for energy)
    h8 kh[4], kl[4];
#pragma unroll
    for (int nt = 0; nt < 4; ++nt) {
        int q = q0 + nt * 16 + ln;
        kh[nt] = *(const h8*)(khi + ((size_t)b * P2 + q) * CQ + quad * 8);
        kl[nt] = *(const h8*)(klo + ((size_t)b * P2 + q) * CQ + quad * 8);
    }

    f4 acc[4][2];
#pragma unroll
    for (int mt = 0; mt < 4; ++mt)
#pragma unroll
        for (int nt = 0; nt < 2; ++nt) acc[mt][nt] = (f4){0.f, 0.f, 0.f, 0.f};

    // q frags for chunk 0: this wave's p-16 tile = w
    h8 cqh, cql;
    {
        size_t r = ((size_t)b * P1 + w * 16 + ln) * CQ + quad * 8;
        cqh = *(const h8*)(qhi + r);
        cql = *(const h8*)(qlo + r);
    }

    const int eg   = w * 2 + (quad >> 1);                 // energy p-granule
    const int ecol = ((eg ^ sw) << 3) + (quad & 1) * 4;

    for (int pc = 0; pc < P1 / 128; ++pc) {
        const int p0v = pc * 128;
        f4 lv = *(const f4*)(linv + (size_t)b * P1 + p0v + w * 16 + quad * 4);

        _Float16* abuf = &att_s[pc & 1][0][0];
        // ---- energy + att for this wave's p-16 tile ----
#pragma unroll
        for (int nt = 0; nt < 4; ++nt) {
            f4 z = {0.f, 0.f, 0.f, 0.f};
            f4 e = MFMA16(cql, kh[nt], z);
            e = MFMA16(cqh, kl[nt], e);
            e = MFMA16(cqh, kh[nt], e);
            h4 pk;
#pragma unroll
            for (int r = 0; r < 4; ++r)
                pk[r] = (_Float16)(__expf(e[r]) * lv[r]);
            *(h4*)&abuf[(nt * 16 + ln) * 128 + ecol] = pk;
        }
        __syncthreads();

        // prefetch next chunk's q frags (overlaps out-GEMM)
        if (pc + 1 < P1 / 128) {
            size_t r = ((size_t)b * P1 + p0v + 128 + w * 16 + ln) * CQ + quad * 8;
            cqh = *(const h8*)(qhi + r);
            cql = *(const h8*)(qlo + r);
        }

        // ---- out GEMM over this p chunk (hi-only v) ----
#pragma unroll
        for (int kk = 0; kk < 128; kk += 32) {
            h8 bf[2];
#pragma unroll
            for (int nt = 0; nt < 2; ++nt) {
                int g2 = (kk >> 3) + quad;
                bf[nt] = *(const h8*)&abuf[(qh_half * 32 + nt * 16 + ln) * 128
                                           + ((g2 ^ sw) << 3)];
            }
            h8 av[4];
#pragma unroll
            for (int mt = 0; mt < 4; ++mt) {
                size_t off = ((size_t)b * C + wc * 64 + mt * 16 + ln) * P1
                           + p0v + kk + quad * 8;
                av[mt] = *(const h8*)(vhi + off);
            }
#pragma unroll
            for (int mt = 0; mt < 4; ++mt)
#pragma unroll
                for (int nt = 0; nt < 2; ++nt)
                    acc[mt][nt] = MFMA16(av[mt], bf[nt], acc[mt][nt]);
        }
        // double-buffer: next chunk's barrier orders its writes vs our reads
    }

    const float alpha = alpha_p[0];
#pragma unroll
    for (int mt = 0; mt < 4; ++mt) {
#pragma unroll
        for (int nt = 0; nt < 2; ++nt) {
            int q = q0 + qh_half * 32 + nt * 16 + ln;
#pragma unroll
            for (int r = 0; r < 4; ++r) {
                int c = wc * 64 + mt * 16 + quad * 4 + r;
                size_t o = ((size_t)b * C + c) * P2 + q;
                out[o] = fmaf(alpha, acc[mt][nt][r], x2[o]);
            }
        }
    }
}

// ---------------------------------------------------------------------------
extern "C" void kernel_launch(void* const* d_in, const int* in_sizes, int n_in,
                              void* d_out, int out_size, void* d_ws, size_t ws_size,
                              hipStream_t stream) {
    const float* x1    = (const float*)d_in[0];
    const float* x2    = (const float*)d_in[1];
    const float* Wq    = (const float*)d_in[2];
    const float* bq    = (const float*)d_in[3];
    const float* Wk    = (const float*)d_in[4];
    const float* bk    = (const float*)d_in[5];
    const float* Wv    = (const float*)d_in[6];
    const float* bv    = (const float*)d_in[7];
    const float* alpha = (const float*)d_in[8];
    float* out = (float*)d_out;

    _Float16* qh = (_Float16*)d_ws;                     // [B][P1][32]
    _Float16* ql = qh + (size_t)B * P1 * CQ;
    _Float16* kh = ql + (size_t)B * P1 * CQ;            // [B][P2][32]
    _Float16* kl = kh + (size_t)B * P2 * CQ;
    _Float16* vh = kl + (size_t)B * P2 * CQ;            // [B][C][P1]
    _Float16* wqh = vh + (size_t)B * C * P1;            // [32][256]
    _Float16* wql = wqh + CQ * C;
    _Float16* wkh = wql + CQ * C;
    _Float16* wkl = wkh + CQ * C;
    _Float16* wvh = wkl + CQ * C;                       // [256][256]
    float*    li  = (float*)(wvh + C * C);              // [B][P1]

    prep_w<<<dim3(32), 256, 0, stream>>>(Wq, Wk, Wv, wqh, wql, wkh, wkl, wvh);
    prep1<<<dim3(B, P1 / 32), 256, 0, stream>>>(x1, wqh, wql, wvh, bq, bv, qh, ql, vh);
    prep2<<<dim3(B, P2 / 32), 256, 0, stream>>>(x2, wkh, wkl, bk, kh, kl);
    stats_l<<<dim3(512), 512, 0, stream>>>(qh, kh, li);
    attn_gemm<<<dim3(512), 512, 0, stream>>>(qh, ql, kh, kl, vh, li, x2, alpha, out);
}